// Round 1
// 440.492 us; speedup vs baseline: 1.0226x; 1.0226x over previous
//
#include <hip/hip_runtime.h>

#define NZ 32
#define NY 1024
#define NX 1024
#define TY 16   // y-rows marched per thread; y-halo refetch ratio = (TY+7)/TY

__device__ __forceinline__ float rcpf(float x) { return __builtin_amdgcn_rcpf(x); }

// Classic Jiang-Shu WENO5 reconstruction at the i+1/2 face (left-biased).
// Single-reciprocal formulation: a_k = c_k / e_k^2 rescaled by e0^2*e1^2*e2^2
// (identical weights mathematically; fp32-safe: e^2 in [1e-12, ~1e8]).
__device__ __forceinline__ float weno5(float qm2, float qm1, float q0, float qp1, float qp2) {
    const float c1312 = 13.0f / 12.0f;
    float t0 = qm2 - 2.0f * qm1 + q0;
    float u0 = qm2 - 4.0f * qm1 + 3.0f * q0;
    float b0 = c1312 * t0 * t0 + 0.25f * u0 * u0;
    float t1 = qm1 - 2.0f * q0 + qp1;
    float u1 = qm1 - qp1;
    float b1 = c1312 * t1 * t1 + 0.25f * u1 * u1;
    float t2 = q0 - 2.0f * qp1 + qp2;
    float u2 = 3.0f * q0 - 4.0f * qp1 + qp2;
    float b2 = c1312 * t2 * t2 + 0.25f * u2 * u2;
    float e0 = 1e-6f + b0;
    float e1 = 1e-6f + b1;
    float e2 = 1e-6f + b2;
    float s0 = e0 * e0, s1 = e1 * e1, s2 = e2 * e2;
    float a0 = 0.1f * (s1 * s2);
    float a1 = 0.6f * (s0 * s2);
    float a2 = 0.3f * (s0 * s1);
    const float c16 = 1.0f / 6.0f;
    float p0 = (2.0f * qm2 - 7.0f * qm1 + 11.0f * q0) * c16;
    float p1 = (-qm1 + 5.0f * q0 + 2.0f * qp1) * c16;
    float p2 = (2.0f * q0 + 5.0f * qp1 - qp2) * c16;
    // 1-ulp hardware reciprocal is far inside the 5.7e-4 tolerance.
    return (a0 * p0 + a1 * p1 + a2 * p2) * rcpf(a0 + a1 + a2);
}

// Upwinded flux at face i+1/2 given the 6-wide stencil q[i-2..i+3] and vel at cell i.
__device__ __forceinline__ float upwind_flux(float vel, float qm2, float qm1, float q0,
                                             float qp1, float qp2, float qp3) {
    bool up = vel >= 0.0f;
    float s0 = up ? qm2 : qp3;
    float s1 = up ? qm1 : qp2;
    float s2 = up ? q0  : qp1;
    float s3 = up ? qp1 : q0;
    float s4 = up ? qp2 : qm1;
    return vel * weno5(s0, s1, s2, s3, s4);
}

__global__ __launch_bounds__(256) void adv_kernel(const float* __restrict__ h,
                                                  const float* __restrict__ u,
                                                  const float* __restrict__ v,
                                                  float* __restrict__ out) {
    const int tid = threadIdx.x;
    const int x  = blockIdx.x * 256 + tid;
    const int z  = blockIdx.z;
    const int y0 = blockIdx.y * TY;
    const size_t zoff = (size_t)z * (NY * NX);
    const float* __restrict__ hz = h + zoff;
    const float* __restrict__ uz = u + zoff;
    const float* __restrict__ vz = v + zoff;
    float* __restrict__ oz = out + zoff;

    if (z == 0 || z == NZ - 1) {
        // whole slab is exactly zero in the reference
#pragma unroll
        for (int t = 0; t < TY; ++t) oz[(y0 + t) * NX + x] = 0.0f;
        return;
    }

    // clamped x-stencil column indices (edge padding), invariant over the y loop
    int xc[7];
#pragma unroll
    for (int k = 0; k < 7; ++k) {
        int xx = x - 3 + k;
        xc[k] = xx < 0 ? 0 : (xx > NX - 1 ? NX - 1 : xx);
    }
    const int xm1 = (x > 0) ? x - 1 : 0;
    const bool xin = (x >= 2) && (x <= NX - 3);
    const bool lane0 = (tid & 63) == 0;

    // rolling y-window: hy[k] = h[z, clamp(y-3+k), x]
    float hy[7];
#pragma unroll
    for (int k = 0; k < 7; ++k) {
        int yy = y0 - 3 + k;
        yy = yy < 0 ? 0 : (yy > NY - 1 ? NY - 1 : yy);
        hy[k] = hz[yy * NX + x];
    }

    // prologue: flux through face y0-1 (stencil rows y0-4..y0+2 == hy[0..5] roles)
    {
    }
    const int ym1 = (y0 > 0) ? y0 - 1 : 0;
    float fn_lo = upwind_flux(vz[ym1 * NX + x], hy[0], hy[1], hy[2], hy[3], hy[4], hy[5]);

#pragma unroll
    for (int t = 0; t < TY; ++t) {
        const int y = y0 + t;
        const int row = y * NX;

        // x stencil for this row (hx3 already in the y-window; rest are L1 hits)
        float hx0 = hz[row + xc[0]];
        float hx1 = hz[row + xc[1]];
        float hx2 = hz[row + xc[2]];
        float hx3 = hy[3];
        float hx4 = hz[row + xc[4]];
        float hx5 = hz[row + xc[5]];
        float hx6 = hz[row + xc[6]];

        // each thread computes ONE x-face flux (at face x); the x-1 face comes
        // from the neighboring lane. Wave lane 0 recomputes its predecessor.
        float fe_hi = upwind_flux(uz[row + x], hx1, hx2, hx3, hx4, hx5, hx6);
        float fe_lo = __shfl_up(fe_hi, 1);
        if (lane0) {
            fe_lo = upwind_flux(uz[row + xm1], hx0, hx1, hx2, hx3, hx4, hx5);
        }

        // y-face flux at face y; face y-1 is last iteration's fn_hi
        float fn_hi = upwind_flux(vz[row + x], hy[1], hy[2], hy[3], hy[4], hy[5], hy[6]);

        const float inv_d = 1.0f / 1000.0f;  // DX == DY
        float val = -((fe_hi - fe_lo) + (fn_hi - fn_lo)) * inv_d;
        bool interior = xin && (y >= 2) && (y <= NY - 3);
        oz[row + x] = interior ? val : 0.0f;

        fn_lo = fn_hi;
        // roll the window (static rotation — no register moves after unroll)
#pragma unroll
        for (int k = 0; k < 6; ++k) hy[k] = hy[k + 1];
        int yn = y + 4;
        yn = yn > NY - 1 ? NY - 1 : yn;
        hy[6] = hz[yn * NX + x];
    }
}

extern "C" void kernel_launch(void* const* d_in, const int* in_sizes, int n_in,
                              void* d_out, int out_size, void* d_ws, size_t ws_size,
                              hipStream_t stream) {
    const float* h = (const float*)d_in[0];
    const float* u = (const float*)d_in[1];
    const float* v = (const float*)d_in[2];
    float* out = (float*)d_out;

    dim3 block(256, 1, 1);
    dim3 grid(NX / 256, NY / TY, NZ);
    adv_kernel<<<grid, block, 0, stream>>>(h, u, v, out);
}

// Round 2
// 396.629 us; speedup vs baseline: 1.1357x; 1.1106x over previous
//
#include <hip/hip_runtime.h>

#define NZ 32
#define NY 1024
#define NX 1024
#define TY 8   // y-rows marched per thread

__device__ __forceinline__ float rcpf(float x) { return __builtin_amdgcn_rcpf(x); }

// Classic Jiang-Shu WENO5 reconstruction at the i+1/2 face (left-biased).
// Single-reciprocal formulation: a_k = c_k / e_k^2 rescaled by e0^2*e1^2*e2^2
// (identical weights mathematically; fp32-safe: e^2 in [1e-12, ~1e8]).
__device__ __forceinline__ float weno5(float qm2, float qm1, float q0, float qp1, float qp2) {
    const float c1312 = 13.0f / 12.0f;
    float t0 = qm2 - 2.0f * qm1 + q0;
    float u0 = qm2 - 4.0f * qm1 + 3.0f * q0;
    float b0 = c1312 * t0 * t0 + 0.25f * u0 * u0;
    float t1 = qm1 - 2.0f * q0 + qp1;
    float u1 = qm1 - qp1;
    float b1 = c1312 * t1 * t1 + 0.25f * u1 * u1;
    float t2 = q0 - 2.0f * qp1 + qp2;
    float u2 = 3.0f * q0 - 4.0f * qp1 + qp2;
    float b2 = c1312 * t2 * t2 + 0.25f * u2 * u2;
    float e0 = 1e-6f + b0, e1 = 1e-6f + b1, e2 = 1e-6f + b2;
    float s0 = e0 * e0, s1 = e1 * e1, s2 = e2 * e2;
    float a0 = 0.1f * (s1 * s2);
    float a1 = 0.6f * (s0 * s2);
    float a2 = 0.3f * (s0 * s1);
    // coefficient-folded candidate polynomials (mul + 2 fma each)
    float p0 = (1.0f / 3.0f) * qm2 + (-7.0f / 6.0f) * qm1 + (11.0f / 6.0f) * q0;
    float p1 = (-1.0f / 6.0f) * qm1 + (5.0f / 6.0f) * q0 + (1.0f / 3.0f) * qp1;
    float p2 = (1.0f / 3.0f) * q0 + (5.0f / 6.0f) * qp1 + (-1.0f / 6.0f) * qp2;
    // 1-ulp hardware reciprocal is far inside the tolerance.
    return (a0 * p0 + a1 * p1 + a2 * p2) * rcpf(a0 + a1 + a2);
}

// Upwinded flux at face i+1/2 given the 6-wide stencil q[i-2..i+3] and vel at cell i.
__device__ __forceinline__ float upwind_flux(float vel, float qm2, float qm1, float q0,
                                             float qp1, float qp2, float qp3) {
    bool up = vel >= 0.0f;
    float s0 = up ? qm2 : qp3;
    float s1 = up ? qm1 : qp2;
    float s2 = up ? q0  : qp1;
    float s3 = up ? qp1 : q0;
    float s4 = up ? qp2 : qm1;
    return vel * weno5(s0, s1, s2, s3, s4);
}

__global__ __launch_bounds__(256) void adv_kernel(const float* __restrict__ h,
                                                  const float* __restrict__ u,
                                                  const float* __restrict__ v,
                                                  float* __restrict__ out) {
    const int tid = threadIdx.x;
    const int px  = blockIdx.x * 256 + tid;   // x-pair index: points x0, x0+1
    const int x0  = px * 2;
    const int z   = blockIdx.z;
    const int y0  = blockIdx.y * TY;
    const size_t zoff = (size_t)z * (NY * NX);
    const float* __restrict__ hz = h + zoff;
    const float* __restrict__ uz = u + zoff;
    const float* __restrict__ vz = v + zoff;
    float* __restrict__ oz = out + zoff;

    if (z == 0 || z == NZ - 1) {
        // whole slab is exactly zero in the reference
#pragma unroll
        for (int t = 0; t < TY; ++t)
            *(float2*)(oz + (y0 + t) * NX + x0) = make_float2(0.0f, 0.0f);
        return;
    }

    // fast path: x-stencil [x0-4 .. x0+5] entirely in-bounds -> pure float2 loads
    const bool xfast = (x0 >= 4) && (x0 <= NX - 6);
    // both pair points interior in x: 2 <= x and x <= NX-3 for x in {x0, x0+1}
    const bool xint  = (px >= 1) && (px <= (NX - 4) / 2);
    const bool lane0 = (tid & 63) == 0;

    // rolling y-window of the pair's own columns: hy[k] = h[z, clamp(y-3+k), x0..x0+1]
    float2 hy[7];
#pragma unroll
    for (int k = 0; k < 7; ++k) {
        int yy = y0 - 3 + k;
        yy = yy < 0 ? 0 : (yy > NY - 1 ? NY - 1 : yy);
        hy[k] = *(const float2*)(hz + yy * NX + x0);
    }

    // prologue: fluxes through face y0-1 for both columns
    const int ym1 = (y0 > 0) ? y0 - 1 : 0;
    float2 vm = *(const float2*)(vz + ym1 * NX + x0);
    float fn_lo_e = upwind_flux(vm.x, hy[0].x, hy[1].x, hy[2].x, hy[3].x, hy[4].x, hy[5].x);
    float fn_lo_o = upwind_flux(vm.y, hy[0].y, hy[1].y, hy[2].y, hy[3].y, hy[4].y, hy[5].y);

#pragma unroll
    for (int t = 0; t < TY; ++t) {
        const int y   = y0 + t;          // uniform across the block -> scalar row base
        const int row = y * NX;
        const float* __restrict__ rp  = hz + row;
        const float* __restrict__ rpu = uz + row;

        // x stencil sl[k] = h[z, y, x0-4+k] (edge-clamped); middle pair from the window
        float sl[10];
        if (xfast) {
            float2 m2  = *(const float2*)(rp + x0 - 4);
            float2 m1  = *(const float2*)(rp + x0 - 2);
            float2 pp1 = *(const float2*)(rp + x0 + 2);
            float2 pp2 = *(const float2*)(rp + x0 + 4);
            sl[0] = m2.x;  sl[1] = m2.y;
            sl[2] = m1.x;  sl[3] = m1.y;
            sl[6] = pp1.x; sl[7] = pp1.y;
            sl[8] = pp2.x; sl[9] = pp2.y;
        } else {
#pragma unroll
            for (int k = 0; k < 10; ++k) {
                if (k == 4 || k == 5) continue;
                int xx = x0 - 4 + k;
                xx = xx < 0 ? 0 : (xx > NX - 1 ? NX - 1 : xx);
                sl[k] = rp[xx];
            }
        }
        sl[4] = hy[3].x;
        sl[5] = hy[3].y;

        float2 uv = *(const float2*)(rpu + x0);
        float2 vv = *(const float2*)(vz + row + x0);

        // fluxes through faces x0 (even) and x0+1 (odd)
        float f_e = upwind_flux(uv.x, sl[2], sl[3], sl[4], sl[5], sl[6], sl[7]);
        float f_o = upwind_flux(uv.y, sl[3], sl[4], sl[5], sl[6], sl[7], sl[8]);

        // west face of the even point = odd-face flux of lane-1; wave lane 0
        // recomputes it (stencil already in registers, vel is one scalar load)
        float fe_lo = __shfl_up(f_o, 1);
        if (lane0) {
            int xm = x0 - 1;
            xm = xm < 0 ? 0 : xm;
            fe_lo = upwind_flux(rpu[xm], sl[1], sl[2], sl[3], sl[4], sl[5], sl[6]);
        }

        // y-direction fluxes through face y for both columns
        float fn_e = upwind_flux(vv.x, hy[1].x, hy[2].x, hy[3].x, hy[4].x, hy[5].x, hy[6].x);
        float fn_o = upwind_flux(vv.y, hy[1].y, hy[2].y, hy[3].y, hy[4].y, hy[5].y, hy[6].y);

        const float inv_d = 1.0f / 1000.0f;  // DX == DY
        bool yin = (y >= 2) && (y <= NY - 3);
        bool wr  = xint && yin;
        float2 res;
        res.x = wr ? -((f_e - fe_lo) + (fn_e - fn_lo_e)) * inv_d : 0.0f;
        res.y = wr ? -((f_o - f_e) + (fn_o - fn_lo_o)) * inv_d : 0.0f;
        *(float2*)(oz + row + x0) = res;

        fn_lo_e = fn_e;
        fn_lo_o = fn_o;
        // roll the window (static rotation — free after full unroll)
#pragma unroll
        for (int k = 0; k < 6; ++k) hy[k] = hy[k + 1];
        int yn = y + 4;
        yn = yn > NY - 1 ? NY - 1 : yn;
        hy[6] = *(const float2*)(hz + yn * NX + x0);
    }
}

extern "C" void kernel_launch(void* const* d_in, const int* in_sizes, int n_in,
                              void* d_out, int out_size, void* d_ws, size_t ws_size,
                              hipStream_t stream) {
    const float* h = (const float*)d_in[0];
    const float* u = (const float*)d_in[1];
    const float* v = (const float*)d_in[2];
    float* out = (float*)d_out;

    dim3 block(256, 1, 1);
    dim3 grid(NX / 512, NY / TY, NZ);   // 2 x 128 x 32 blocks, 2 points/thread in x
    adv_kernel<<<grid, block, 0, stream>>>(h, u, v, out);
}